// Round 4
// baseline (2014.510 us; speedup 1.0000x reference)
//
#include <hip/hip_runtime.h>
#include <hip/hip_bf16.h>

typedef unsigned short u16;
typedef unsigned int u32;
typedef __attribute__((ext_vector_type(8))) short bf8;
typedef __attribute__((ext_vector_type(2))) unsigned int u32x2;
typedef __attribute__((ext_vector_type(4))) float f32x4;

__device__ __forceinline__ float bf2f(u16 u) {
    u32 v = ((u32)u) << 16;
    float f;
    __builtin_memcpy(&f, &v, 4);
    return f;
}
__device__ __forceinline__ u16 f2bf(float f) {
    u32 v;
    __builtin_memcpy(&v, &f, 4);
    u32 r = (v + 0x7fffu + ((v >> 16) & 1u)) >> 16;
    return (u16)r;
}
__device__ __forceinline__ u32 pk2(float a, float b) {
    return (u32)f2bf(a) | ((u32)f2bf(b) << 16);
}

#define BM 128
#define BN 128
#define BK 64
#define LSTR 72   // 64 + 8 pad: rows shift 4 banks -> only 2-way aliasing (free)

// Detect whether float inputs are fp32 (flag=1) or bf16 (flag=0).
__global__ void detect_dtype(const u16* __restrict__ v, int* __restrict__ flag)
{
    __shared__ int red[256];
    int tid = threadIdx.x;
    int cnt = 0;
    for (int i = tid; i < 8192; i += 256) {
        u16 u = v[2 * i];
        int e = (u >> 7) & 0xFF;
        cnt += (e >= 160) ? 1 : 0;
    }
    red[tid] = cnt;
    __syncthreads();
    for (int s = 128; s > 0; s >>= 1) {
        if (tid < s) red[tid] += red[tid + s];
        __syncthreads();
    }
    if (tid == 0) flag[0] = (red[0] > 400) ? 1 : 0;
}

// C[M][Ncols] = A[M][K] @ W[Ncols][K]^T   (bf16/f32 in, bf16 out, fp32 accum)
// blockIdx.y = m-block, blockIdx.x = n-block (x fast => column blocks of the
// same row tile run back-to-back and share the A tile through L2/L3).
__global__ __launch_bounds__(256)
void gemm_bt(const void* __restrict__ Av, const u16* __restrict__ W,
             u16* __restrict__ C, const int* __restrict__ flag,
             int M, int K, int Ncols)
{
    __shared__ u16 As[BM][LSTR];
    __shared__ u16 Ws[BN][LSTR];
    const bool isf32 = flag[0] != 0;
    const int tid = threadIdx.x;
    const int m0 = blockIdx.y * BM;
    const int n0 = blockIdx.x * BN;
    const int wave = tid >> 6, lane = tid & 63;
    const int l16 = lane & 15, quad = lane >> 4;
    const int wrow = (wave >> 1) * 64, wcol = (wave & 1) * 64;

    f32x4 acc[4][4];
    for (int mi = 0; mi < 4; ++mi)
        for (int ni = 0; ni < 4; ++ni)
            for (int r = 0; r < 4; ++r) acc[mi][ni][r] = 0.f;

    for (int kk = 0; kk < K; kk += BK) {
        for (int it = 0; it < 4; ++it) {
            int c = tid + it * 256;
            int row = c >> 3, col8 = (c & 7) * 8;
            uint4 v = make_uint4(0, 0, 0, 0);
            int gr = m0 + row;
            if (gr < M) {
                if (!isf32) {
                    v = *(const uint4*)((const u16*)Av + (size_t)gr * K + (kk + col8));
                } else {
                    const float* Af = (const float*)Av + (size_t)gr * K + (kk + col8);
                    float4 x = *(const float4*)Af;
                    float4 y = *(const float4*)(Af + 4);
                    v = make_uint4(pk2(x.x, x.y), pk2(x.z, x.w), pk2(y.x, y.y), pk2(y.z, y.w));
                }
            }
            *(uint4*)(&As[row][col8]) = v;
        }
        for (int it = 0; it < 4; ++it) {
            int c = tid + it * 256;
            int row = c >> 3, col8 = (c & 7) * 8;
            uint4 v = *(const uint4*)(W + (size_t)(n0 + row) * K + (kk + col8));
            *(uint4*)(&Ws[row][col8]) = v;
        }
        __syncthreads();
        for (int ko = 0; ko < BK; ko += 32) {
            bf8 af[4], bw[4];
            for (int mi = 0; mi < 4; ++mi)
                af[mi] = *(const bf8*)(&As[wrow + mi * 16 + l16][ko + quad * 8]);
            for (int ni = 0; ni < 4; ++ni)
                bw[ni] = *(const bf8*)(&Ws[wcol + ni * 16 + l16][ko + quad * 8]);
            for (int mi = 0; mi < 4; ++mi)
                for (int ni = 0; ni < 4; ++ni)
                    acc[mi][ni] = __builtin_amdgcn_mfma_f32_16x16x32_bf16(
                        af[mi], bw[ni], acc[mi][ni], 0, 0, 0);
        }
        __syncthreads();
    }
    // C/D layout: col = lane&15, row = quad*4 + reg  (m89-verified)
    for (int mi = 0; mi < 4; ++mi) {
        int rbase = m0 + wrow + mi * 16 + quad * 4;
        for (int r = 0; r < 4; ++r) {
            int row = rbase + r;
            if (row >= M) continue;
            for (int ni = 0; ni < 4; ++ni) {
                int col = n0 + wcol + ni * 16 + l16;
                C[(size_t)row * Ncols + col] = f2bf(acc[mi][ni][r]);
            }
        }
    }
}

// In-place: CG[t][p] += Vout[j][p] + Eout[k][p] + Vout[i][256+p]; BN partial stats.
// CG accesses are non-temporal: streaming 1 GB that must not evict the
// randomly-gathered Vout/Eout (307 MB) from L3.
__global__ __launch_bounds__(256)
void gather_stats(u16* __restrict__ CG, const u16* __restrict__ Vout,
                  const u16* __restrict__ Eout,
                  const int* __restrict__ jidx, const int* __restrict__ kidx,
                  const int* __restrict__ iidx, float* __restrict__ stats, int T)
{
    const int tid = threadIdx.x;
    const int q = tid & 63;
    const int wv = tid >> 6;
    const int p = q * 4;
    float sum[4] = {0.f, 0.f, 0.f, 0.f};
    float ssq[4] = {0.f, 0.f, 0.f, 0.f};
    for (long t = (long)blockIdx.x * 4 + wv; t < T; t += (long)gridDim.x * 4) {
        int j = jidx[t], k = kidx[t], i = iidx[t];
        u32x2 ua = __builtin_nontemporal_load((const u32x2*)(CG + t * 256 + p));
        uint2 uj = *(const uint2*)(Vout + (size_t)j * 512 + p);
        uint2 uk = *(const uint2*)(Eout + (size_t)k * 256 + p);
        uint2 ui = *(const uint2*)(Vout + (size_t)i * 512 + 256 + p);
        float v[4];
        v[0] = bf2f((u16)(ua[0] & 0xffffu)) + bf2f((u16)(uj.x & 0xffffu))
             + bf2f((u16)(uk.x & 0xffffu)) + bf2f((u16)(ui.x & 0xffffu));
        v[1] = bf2f((u16)(ua[0] >> 16)) + bf2f((u16)(uj.x >> 16))
             + bf2f((u16)(uk.x >> 16)) + bf2f((u16)(ui.x >> 16));
        v[2] = bf2f((u16)(ua[1] & 0xffffu)) + bf2f((u16)(uj.y & 0xffffu))
             + bf2f((u16)(uk.y & 0xffffu)) + bf2f((u16)(ui.y & 0xffffu));
        v[3] = bf2f((u16)(ua[1] >> 16)) + bf2f((u16)(uj.y >> 16))
             + bf2f((u16)(uk.y >> 16)) + bf2f((u16)(ui.y >> 16));
        for (int x = 0; x < 4; ++x) {
            sum[x] += v[x];
            ssq[x] += v[x] * v[x];
        }
        u32x2 o;
        o[0] = pk2(v[0], v[1]);
        o[1] = pk2(v[2], v[3]);
        __builtin_nontemporal_store(o, (u32x2*)(CG + t * 256 + p));
    }
    __shared__ float red[512];
    red[tid] = 0.f;
    red[tid + 256] = 0.f;
    __syncthreads();
    for (int x = 0; x < 4; ++x) {
        atomicAdd(&red[p + x], sum[x]);
        atomicAdd(&red[256 + p + x], ssq[x]);
    }
    __syncthreads();
    atomicAdd(&stats[tid], red[tid]);
    atomicAdd(&stats[tid + 256], red[tid + 256]);
}

__global__ void bn_finalize(const float* __restrict__ stats,
                            const void* __restrict__ gc, const void* __restrict__ bc,
                            const void* __restrict__ gg, const void* __restrict__ bg,
                            float* __restrict__ ab, const int* __restrict__ flag,
                            float invT)
{
    const bool isf32 = flag[0] != 0;
    int p = threadIdx.x;  // 256
    float mean = stats[p] * invT;
    float var = stats[256 + p] * invT - mean * mean;
    const void* gsrc = (p < 128) ? gc : gg;
    const void* bsrc = (p < 128) ? bc : bg;
    int pi = p & 127;
    float g = isf32 ? ((const float*)gsrc)[pi] : bf2f(((const u16*)gsrc)[pi]);
    float b = isf32 ? ((const float*)bsrc)[pi] : bf2f(((const u16*)bsrc)[pi]);
    float a = g * rsqrtf(var + 1e-5f);
    ab[p] = a;
    ab[256 + p] = b - mean * a;
}

// ---------- CSR build for k_idx (scatter -> gather inversion) ----------

__global__ __launch_bounds__(256)
void hist_k(const int* __restrict__ kidx, int* __restrict__ cnt, int T)
{
    for (int t = blockIdx.x * 256 + threadIdx.x; t < T; t += gridDim.x * 256)
        atomicAdd(&cnt[kidx[t]], 1);
}

#define SCHUNK 2048  // elements per scan block (256 thr x 8)

__global__ __launch_bounds__(256)
void scan_blocks(const int* __restrict__ cnt, int* __restrict__ bsum, int E)
{
    __shared__ int red[256];
    int b = blockIdx.x, t = threadIdx.x;
    int base = b * SCHUNK + t * 8;
    int s = 0;
    for (int i = 0; i < 8; ++i) {
        int idx = base + i;
        s += (idx < E) ? cnt[idx] : 0;
    }
    red[t] = s;
    __syncthreads();
    for (int st = 128; st > 0; st >>= 1) {
        if (t < st) red[t] += red[t + st];
        __syncthreads();
    }
    if (t == 0) bsum[b] = red[0];
}

// single block: exclusive scan of bsum[0..NB) in place (NB <= 256); offs[E] = T
__global__ void scan_partials(int* __restrict__ bsum, int NB,
                              int* __restrict__ offs, int E, int T)
{
    __shared__ int sh[256];
    int t = threadIdx.x;
    int v = (t < NB) ? bsum[t] : 0;
    sh[t] = v;
    __syncthreads();
    for (int d = 1; d < 256; d <<= 1) {
        int x = (t >= d) ? sh[t - d] : 0;
        __syncthreads();
        sh[t] += x;
        __syncthreads();
    }
    if (t < NB) bsum[t] = sh[t] - v;   // exclusive
    if (t == 0) offs[E] = T;
}

__global__ __launch_bounds__(256)
void scan_chunks(const int* __restrict__ cnt, const int* __restrict__ bsum,
                 int* __restrict__ offs, int E)
{
    __shared__ int sh[256];
    int b = blockIdx.x, t = threadIdx.x;
    int base = b * SCHUNK + t * 8;
    int loc[8];
    int s = 0;
    for (int i = 0; i < 8; ++i) {
        int idx = base + i;
        loc[i] = (idx < E) ? cnt[idx] : 0;
    }
    for (int i = 0; i < 8; ++i) { int v = loc[i]; loc[i] = s; s += v; }
    sh[t] = s;
    __syncthreads();
    for (int d = 1; d < 256; d <<= 1) {
        int x = (t >= d) ? sh[t - d] : 0;
        __syncthreads();
        sh[t] += x;
        __syncthreads();
    }
    int ex = sh[t] - s;                // exclusive over threads
    int off = bsum[b] + ex;
    for (int i = 0; i < 8; ++i) {
        int idx = base + i;
        if (idx < E) offs[idx] = off + loc[i];
    }
}

__global__ __launch_bounds__(256)
void fill_k(const int* __restrict__ kidx, const int* __restrict__ offs,
            int* __restrict__ cur, int* __restrict__ blist, int T)
{
    for (int t = blockIdx.x * 256 + threadIdx.x; t < T; t += gridDim.x * 256) {
        int k = kidx[t];
        int pos = offs[k] + atomicAdd(&cur[k], 1);
        blist[pos] = t;
    }
}

// Fused: update = silu(bn(core)) * sigmoid(bn(gate)); segment-sum via CSR into
// a bf16 LDS tile; then Out[tile][128] = tile @ Wo^T + Edge. Eliminates the
// 205 MB f32 acc round-trip (and its memset).
// Phase 1: wave wv computes rows wv*32..wv*32+31 of the 128-row tile; lane q
// holds features 2q,2q+1. bf16 conversion identical to old store->load->pk2.
// Phase 2: standard MFMA GEMM; Wo (bf16, 32 KB, L2-resident) fragments loaded
// directly from global -- no Ws tile.
__global__ __launch_bounds__(256)
void seg_gemm_out(const u16* __restrict__ CG, const float* __restrict__ ab,
                  const int* __restrict__ offs, const int* __restrict__ blist,
                  const u16* __restrict__ Wo, const void* __restrict__ Edgev,
                  void* __restrict__ Outv, const int* __restrict__ flag, int E)
{
    __shared__ u16 As[128][136];   // 34816 B: update tile, K=128 cols + pad
    const bool isf32 = flag[0] != 0;
    const int tid = threadIdx.x;
    const int wave = tid >> 6, lane = tid & 63;
    const int m0 = blockIdx.x * 128;
    const int f = lane * 2;

    {
        const float ac0 = ab[f], ac1 = ab[f + 1];
        const float ag0 = ab[128 + f], ag1 = ab[128 + f + 1];
        const float bc0 = ab[256 + f], bc1 = ab[256 + f + 1];
        const float bg0 = ab[384 + f], bg1 = ab[384 + f + 1];
        for (int i = 0; i < 32; ++i) {
            int rl = wave * 32 + i;
            int e = m0 + rl;
            float u0 = 0.f, u1 = 0.f;
            if (e < E) {
                int s = offs[e], en = offs[e + 1];
                for (int idx = s; idx < en; ++idx) {
                    int t = blist[idx];
                    u32 c2 = __builtin_nontemporal_load(
                        (const u32*)(CG + (size_t)t * 256 + f));
                    u32 g2 = __builtin_nontemporal_load(
                        (const u32*)(CG + (size_t)t * 256 + 128 + f));
                    float c0 = bf2f((u16)(c2 & 0xffffu)) * ac0 + bc0;
                    float c1 = bf2f((u16)(c2 >> 16)) * ac1 + bc1;
                    float g0 = bf2f((u16)(g2 & 0xffffu)) * ag0 + bg0;
                    float g1 = bf2f((u16)(g2 >> 16)) * ag1 + bg1;
                    float s0 = 1.f / (1.f + __expf(-c0));
                    float s1 = 1.f / (1.f + __expf(-c1));
                    float t0 = 1.f / (1.f + __expf(-g0));
                    float t1 = 1.f / (1.f + __expf(-g1));
                    u0 += c0 * s0 * t0;
                    u1 += c1 * s1 * t1;
                }
            }
            *(u32*)(&As[rl][f]) = pk2(u0, u1);
        }
    }
    __syncthreads();

    const int l16 = lane & 15, quad = lane >> 4;
    const int wrow = (wave >> 1) * 64, wcol = (wave & 1) * 64;
    f32x4 acc[4][4];
    for (int mi = 0; mi < 4; ++mi)
        for (int ni = 0; ni < 4; ++ni)
            for (int r = 0; r < 4; ++r) acc[mi][ni][r] = 0.f;

    for (int kk = 0; kk < 128; kk += 32) {
        bf8 af[4], bw[4];
        for (int mi = 0; mi < 4; ++mi)
            af[mi] = *(const bf8*)(&As[wrow + mi * 16 + l16][kk + quad * 8]);
        for (int ni = 0; ni < 4; ++ni)
            bw[ni] = *(const bf8*)(Wo + (size_t)(wcol + ni * 16 + l16) * 128
                                       + kk + quad * 8);
        for (int mi = 0; mi < 4; ++mi)
            for (int ni = 0; ni < 4; ++ni)
                acc[mi][ni] = __builtin_amdgcn_mfma_f32_16x16x32_bf16(
                    af[mi], bw[ni], acc[mi][ni], 0, 0, 0);
    }

    for (int mi = 0; mi < 4; ++mi) {
        int rbase = m0 + wrow + mi * 16 + quad * 4;
        for (int r = 0; r < 4; ++r) {
            int row = rbase + r;
            if (row >= E) continue;
            for (int ni = 0; ni < 4; ++ni) {
                int col = wcol + ni * 16 + l16;
                size_t idx = (size_t)row * 128 + col;
                float e = isf32 ? ((const float*)Edgev)[idx] : bf2f(((const u16*)Edgev)[idx]);
                float v = acc[mi][ni][r] + e;
                if (isf32) ((float*)Outv)[idx] = v;
                else       ((u16*)Outv)[idx] = f2bf(v);
            }
        }
    }
}

// Wv rows: [0:128)=w_core_src [128:256)=w_gate_src [256:384)=w_core_dst [384:512)=w_gate_dst
// We rows: [0:128)=w_core_bond [128:256)=w_gate_bond
// Wa rows: [0:128)=w_core_angle [128:256)=w_gate_angle (K=64)
// Wo: w_out [128][128]
__device__ __forceinline__ u16 ld_bf(const void* p, size_t idx, bool isf32)
{
    return isf32 ? f2bf(((const float*)p)[idx]) : ((const u16*)p)[idx];
}

__global__ void pack_weights(const void* __restrict__ wcs, const void* __restrict__ wcd,
                             const void* __restrict__ wcb, const void* __restrict__ wca,
                             const void* __restrict__ wgs, const void* __restrict__ wgd,
                             const void* __restrict__ wgb, const void* __restrict__ wga,
                             const void* __restrict__ wout,
                             u16* __restrict__ Wv, u16* __restrict__ We,
                             u16* __restrict__ Wa, u16* __restrict__ Wo,
                             const int* __restrict__ flag)
{
    const bool isf32 = flag[0] != 0;
    int tid = blockIdx.x * 256 + threadIdx.x;  // 65536 threads
    {
        int row = tid >> 7, col = tid & 127;
        const void* src = (row < 128) ? wcs : (row < 256) ? wgs : (row < 384) ? wcd : wgd;
        Wv[tid] = ld_bf(src, (size_t)(row & 127) * 128 + col, isf32);
    }
    if (tid < 256 * 128) {
        int row = tid >> 7, col = tid & 127;
        const void* src = (row < 128) ? wcb : wgb;
        We[tid] = ld_bf(src, (size_t)(row & 127) * 128 + col, isf32);
    }
    if (tid < 256 * 64) {
        int row = tid >> 6, col = tid & 63;
        const void* src = (row < 128) ? wca : wga;
        Wa[tid] = ld_bf(src, (size_t)(row & 127) * 64 + col, isf32);
    }
    if (tid < 128 * 128) {
        Wo[tid] = ld_bf(wout, (size_t)tid, isf32);
    }
}

extern "C" void kernel_launch(void* const* d_in, const int* in_sizes, int n_in,
                              void* d_out, int out_size, void* d_ws, size_t ws_size,
                              hipStream_t stream)
{
    const void* vertex = d_in[0];
    const void* edge   = d_in[1];
    const void* angle  = d_in[2];
    // d_in[3] = edge_index (unused by the reference computation)
    const int* kidx = (const int*)d_in[4];
    const int* jidx = (const int*)d_in[5];
    const int* iidx = (const int*)d_in[6];

    const int N = in_sizes[0] / 128;
    const int E = in_sizes[1] / 128;
    const int T = in_sizes[2] / 64;

    char* p = (char*)d_ws;
    auto alloc = [&](size_t bytes) {
        char* r = p;
        p += (bytes + 255) & ~(size_t)255;
        return r;
    };
    u16* Wv = (u16*)alloc((size_t)512 * 128 * 2);
    u16* We = (u16*)alloc((size_t)256 * 128 * 2);
    u16* Wa = (u16*)alloc((size_t)256 * 64 * 2);
    u16* Wo = (u16*)alloc((size_t)128 * 128 * 2);
    float* stats = (float*)alloc(512 * 4);
    float* ab = (float*)alloc(512 * 4);
    int* flag = (int*)alloc(256);
    u16* Vout = (u16*)alloc((size_t)N * 512 * 2);   // dead after gather_stats
    u16* Eout = (u16*)alloc((size_t)E * 256 * 2);   // dead after gather_stats
    u16* CG   = (u16*)alloc((size_t)T * 256 * 2);   // angle GEMM out, then core|gate in place

    // CSR arrays overlay the dead Vout region (built after gather_stats).
    int* cnt   = (int*)Vout;                        // E ints (histogram, then cursor)
    int* offs  = cnt + ((E + 63) & ~63);            // E+1 ints
    int* blist = offs + ((E + 1 + 63) & ~63);       // T ints
    int* bsum  = blist + ((T + 63) & ~63);          // <=256 ints
    const int NB = (E + SCHUNK - 1) / SCHUNK;       // 196 for E=400000 (<=256)

    hipMemsetAsync(stats, 0, 512 * 4, stream);
    detect_dtype<<<1, 256, 0, stream>>>((const u16*)vertex, flag);
    pack_weights<<<256, 256, 0, stream>>>(d_in[7], d_in[8], d_in[9], d_in[10],
                                          d_in[11], d_in[12], d_in[13], d_in[14],
                                          d_in[19], Wv, We, Wa, Wo, flag);
    gemm_bt<<<dim3(4, (N + 127) / 128), 256, 0, stream>>>(vertex, Wv, Vout, flag, N, 128, 512);
    gemm_bt<<<dim3(2, (E + 127) / 128), 256, 0, stream>>>(edge, We, Eout, flag, E, 128, 256);
    gemm_bt<<<dim3(2, (T + 127) / 128), 256, 0, stream>>>(angle, Wa, CG, flag, T, 64, 256);
    gather_stats<<<2048, 256, 0, stream>>>(CG, Vout, Eout, jidx, kidx, iidx, stats, T);

    // Vout/Eout dead: build CSR of kidx in the freed region.
    hipMemsetAsync(cnt, 0, (size_t)E * 4, stream);
    hist_k<<<2048, 256, 0, stream>>>(kidx, cnt, T);
    scan_blocks<<<NB, 256, 0, stream>>>(cnt, bsum, E);
    scan_partials<<<1, 256, 0, stream>>>(bsum, NB, offs, E, T);
    scan_chunks<<<NB, 256, 0, stream>>>(cnt, bsum, offs, E);
    hipMemsetAsync(cnt, 0, (size_t)E * 4, stream);  // reuse as fill cursor
    fill_k<<<2048, 256, 0, stream>>>(kidx, offs, cnt, blist, T);

    bn_finalize<<<1, 256, 0, stream>>>(stats, d_in[15], d_in[16], d_in[17], d_in[18],
                                       ab, flag, 1.0f / (float)T);
    seg_gemm_out<<<(E + 127) / 128, 256, 0, stream>>>(CG, ab, offs, blist, Wo,
                                                      edge, d_out, flag, E);
}

// Round 5
// 1872.931 us; speedup vs baseline: 1.0756x; 1.0756x over previous
//
#include <hip/hip_runtime.h>
#include <hip/hip_bf16.h>

typedef unsigned short u16;
typedef unsigned int u32;
typedef __attribute__((ext_vector_type(8))) short bf8;
typedef __attribute__((ext_vector_type(2))) unsigned int u32x2;
typedef __attribute__((ext_vector_type(4))) float f32x4;

__device__ __forceinline__ float bf2f(u16 u) {
    u32 v = ((u32)u) << 16;
    float f;
    __builtin_memcpy(&f, &v, 4);
    return f;
}
__device__ __forceinline__ u16 f2bf(float f) {
    u32 v;
    __builtin_memcpy(&v, &f, 4);
    u32 r = (v + 0x7fffu + ((v >> 16) & 1u)) >> 16;
    return (u16)r;
}
__device__ __forceinline__ u32 pk2(float a, float b) {
    return (u32)f2bf(a) | ((u32)f2bf(b) << 16);
}

#define BM 128
#define BN 128
#define BK 64
#define LSTR 72   // 64 + 8 pad: rows shift 4 banks -> only 2-way aliasing (free)

// Detect whether float inputs are fp32 (flag=1) or bf16 (flag=0).
__global__ void detect_dtype(const u16* __restrict__ v, int* __restrict__ flag)
{
    __shared__ int red[256];
    int tid = threadIdx.x;
    int cnt = 0;
    for (int i = tid; i < 8192; i += 256) {
        u16 u = v[2 * i];
        int e = (u >> 7) & 0xFF;
        cnt += (e >= 160) ? 1 : 0;
    }
    red[tid] = cnt;
    __syncthreads();
    for (int s = 128; s > 0; s >>= 1) {
        if (tid < s) red[tid] += red[tid + s];
        __syncthreads();
    }
    if (tid == 0) flag[0] = (red[0] > 400) ? 1 : 0;
}

// C[M][Ncols] = A[M][K] @ W[Ncols][K]^T   (bf16/f32 in, bf16 out, fp32 accum)
// blockIdx.y = m-block, blockIdx.x = n-block (x fast => column blocks of the
// same row tile run back-to-back and share the A tile through L2/L3).
__global__ __launch_bounds__(256)
void gemm_bt(const void* __restrict__ Av, const u16* __restrict__ W,
             u16* __restrict__ C, const int* __restrict__ flag,
             int M, int K, int Ncols)
{
    __shared__ u16 As[BM][LSTR];
    __shared__ u16 Ws[BN][LSTR];
    const bool isf32 = flag[0] != 0;
    const int tid = threadIdx.x;
    const int m0 = blockIdx.y * BM;
    const int n0 = blockIdx.x * BN;
    const int wave = tid >> 6, lane = tid & 63;
    const int l16 = lane & 15, quad = lane >> 4;
    const int wrow = (wave >> 1) * 64, wcol = (wave & 1) * 64;

    f32x4 acc[4][4];
    for (int mi = 0; mi < 4; ++mi)
        for (int ni = 0; ni < 4; ++ni)
            for (int r = 0; r < 4; ++r) acc[mi][ni][r] = 0.f;

    for (int kk = 0; kk < K; kk += BK) {
        for (int it = 0; it < 4; ++it) {
            int c = tid + it * 256;
            int row = c >> 3, col8 = (c & 7) * 8;
            uint4 v = make_uint4(0, 0, 0, 0);
            int gr = m0 + row;
            if (gr < M) {
                if (!isf32) {
                    v = *(const uint4*)((const u16*)Av + (size_t)gr * K + (kk + col8));
                } else {
                    const float* Af = (const float*)Av + (size_t)gr * K + (kk + col8);
                    float4 x = *(const float4*)Af;
                    float4 y = *(const float4*)(Af + 4);
                    v = make_uint4(pk2(x.x, x.y), pk2(x.z, x.w), pk2(y.x, y.y), pk2(y.z, y.w));
                }
            }
            *(uint4*)(&As[row][col8]) = v;
        }
        for (int it = 0; it < 4; ++it) {
            int c = tid + it * 256;
            int row = c >> 3, col8 = (c & 7) * 8;
            uint4 v = *(const uint4*)(W + (size_t)(n0 + row) * K + (kk + col8));
            *(uint4*)(&Ws[row][col8]) = v;
        }
        __syncthreads();
        for (int ko = 0; ko < BK; ko += 32) {
            bf8 af[4], bw[4];
            for (int mi = 0; mi < 4; ++mi)
                af[mi] = *(const bf8*)(&As[wrow + mi * 16 + l16][ko + quad * 8]);
            for (int ni = 0; ni < 4; ++ni)
                bw[ni] = *(const bf8*)(&Ws[wcol + ni * 16 + l16][ko + quad * 8]);
            for (int mi = 0; mi < 4; ++mi)
                for (int ni = 0; ni < 4; ++ni)
                    acc[mi][ni] = __builtin_amdgcn_mfma_f32_16x16x32_bf16(
                        af[mi], bw[ni], acc[mi][ni], 0, 0, 0);
        }
        __syncthreads();
    }
    // C/D layout: col = lane&15, row = quad*4 + reg  (m89-verified)
    for (int mi = 0; mi < 4; ++mi) {
        int rbase = m0 + wrow + mi * 16 + quad * 4;
        for (int r = 0; r < 4; ++r) {
            int row = rbase + r;
            if (row >= M) continue;
            for (int ni = 0; ni < 4; ++ni) {
                int col = n0 + wcol + ni * 16 + l16;
                C[(size_t)row * Ncols + col] = f2bf(acc[mi][ni][r]);
            }
        }
    }
}

__device__ __forceinline__ void gs_body(u32x2 ua, uint2 uj, uint2 uk, uint2 ui,
                                        float* v)
{
    v[0] = bf2f((u16)(ua[0] & 0xffffu)) + bf2f((u16)(uj.x & 0xffffu))
         + bf2f((u16)(uk.x & 0xffffu)) + bf2f((u16)(ui.x & 0xffffu));
    v[1] = bf2f((u16)(ua[0] >> 16)) + bf2f((u16)(uj.x >> 16))
         + bf2f((u16)(uk.x >> 16)) + bf2f((u16)(ui.x >> 16));
    v[2] = bf2f((u16)(ua[1] & 0xffffu)) + bf2f((u16)(uj.y & 0xffffu))
         + bf2f((u16)(uk.y & 0xffffu)) + bf2f((u16)(ui.y & 0xffffu));
    v[3] = bf2f((u16)(ua[1] >> 16)) + bf2f((u16)(uj.y >> 16))
         + bf2f((u16)(uk.y >> 16)) + bf2f((u16)(ui.y >> 16));
}

// In-place: CG[t][p] += Vout[j][p] + Eout[k][p] + Vout[i][256+p]; BN partial stats.
// 2-deep software pipeline: indices + all 8 row-gathers for two t's issued
// before either is consumed (doubles outstanding loads per wave; the plain
// loop kept only one iteration in flight -> 3.7 TB/s ceiling).
__global__ __launch_bounds__(256)
void gather_stats(u16* __restrict__ CG, const u16* __restrict__ Vout,
                  const u16* __restrict__ Eout,
                  const int* __restrict__ jidx, const int* __restrict__ kidx,
                  const int* __restrict__ iidx, float* __restrict__ stats, int T)
{
    const int tid = threadIdx.x;
    const int q = tid & 63;
    const int wv = tid >> 6;
    const int p = q * 4;
    float sum[4] = {0.f, 0.f, 0.f, 0.f};
    float ssq[4] = {0.f, 0.f, 0.f, 0.f};
    const long stride = (long)gridDim.x * 4;
    const long base = (long)blockIdx.x * 4 + wv;
    for (long t = base; t < T; t += 2 * stride) {
        const long t2 = t + stride;
        const bool h2 = (t2 < T);
        int j1 = jidx[t], k1 = kidx[t], i1 = iidx[t];
        int j2 = h2 ? jidx[t2] : 0;
        int k2 = h2 ? kidx[t2] : 0;
        int i2 = h2 ? iidx[t2] : 0;
        u32x2 ua1 = __builtin_nontemporal_load((const u32x2*)(CG + t * 256 + p));
        uint2 uj1 = *(const uint2*)(Vout + (size_t)j1 * 512 + p);
        uint2 uk1 = *(const uint2*)(Eout + (size_t)k1 * 256 + p);
        uint2 ui1 = *(const uint2*)(Vout + (size_t)i1 * 512 + 256 + p);
        u32x2 ua2 = {0, 0};
        uint2 uj2 = make_uint2(0, 0), uk2 = make_uint2(0, 0), ui2 = make_uint2(0, 0);
        if (h2) {
            ua2 = __builtin_nontemporal_load((const u32x2*)(CG + t2 * 256 + p));
            uj2 = *(const uint2*)(Vout + (size_t)j2 * 512 + p);
            uk2 = *(const uint2*)(Eout + (size_t)k2 * 256 + p);
            ui2 = *(const uint2*)(Vout + (size_t)i2 * 512 + 256 + p);
        }
        float v[4];
        gs_body(ua1, uj1, uk1, ui1, v);
        for (int x = 0; x < 4; ++x) { sum[x] += v[x]; ssq[x] += v[x] * v[x]; }
        u32x2 o1;
        o1[0] = pk2(v[0], v[1]);
        o1[1] = pk2(v[2], v[3]);
        __builtin_nontemporal_store(o1, (u32x2*)(CG + t * 256 + p));
        if (h2) {
            gs_body(ua2, uj2, uk2, ui2, v);
            for (int x = 0; x < 4; ++x) { sum[x] += v[x]; ssq[x] += v[x] * v[x]; }
            u32x2 o2;
            o2[0] = pk2(v[0], v[1]);
            o2[1] = pk2(v[2], v[3]);
            __builtin_nontemporal_store(o2, (u32x2*)(CG + t2 * 256 + p));
        }
    }
    __shared__ float red[512];
    red[tid] = 0.f;
    red[tid + 256] = 0.f;
    __syncthreads();
    for (int x = 0; x < 4; ++x) {
        atomicAdd(&red[p + x], sum[x]);
        atomicAdd(&red[256 + p + x], ssq[x]);
    }
    __syncthreads();
    atomicAdd(&stats[tid], red[tid]);
    atomicAdd(&stats[tid + 256], red[tid + 256]);
}

__global__ void bn_finalize(const float* __restrict__ stats,
                            const void* __restrict__ gc, const void* __restrict__ bc,
                            const void* __restrict__ gg, const void* __restrict__ bg,
                            float* __restrict__ ab, const int* __restrict__ flag,
                            float invT)
{
    const bool isf32 = flag[0] != 0;
    int p = threadIdx.x;  // 256
    float mean = stats[p] * invT;
    float var = stats[256 + p] * invT - mean * mean;
    const void* gsrc = (p < 128) ? gc : gg;
    const void* bsrc = (p < 128) ? bc : bg;
    int pi = p & 127;
    float g = isf32 ? ((const float*)gsrc)[pi] : bf2f(((const u16*)gsrc)[pi]);
    float b = isf32 ? ((const float*)bsrc)[pi] : bf2f(((const u16*)bsrc)[pi]);
    float a = g * rsqrtf(var + 1e-5f);
    ab[p] = a;
    ab[256 + p] = b - mean * a;
}

// ---------- CSR build for k_idx (scatter -> gather inversion) ----------

__global__ __launch_bounds__(256)
void hist_k(const int* __restrict__ kidx, int* __restrict__ cnt, int T)
{
    for (int t = blockIdx.x * 256 + threadIdx.x; t < T; t += gridDim.x * 256)
        atomicAdd(&cnt[kidx[t]], 1);
}

#define SCHUNK 2048  // elements per scan block (256 thr x 8)

__global__ __launch_bounds__(256)
void scan_blocks(const int* __restrict__ cnt, int* __restrict__ bsum, int E)
{
    __shared__ int red[256];
    int b = blockIdx.x, t = threadIdx.x;
    int base = b * SCHUNK + t * 8;
    int s = 0;
    for (int i = 0; i < 8; ++i) {
        int idx = base + i;
        s += (idx < E) ? cnt[idx] : 0;
    }
    red[t] = s;
    __syncthreads();
    for (int st = 128; st > 0; st >>= 1) {
        if (t < st) red[t] += red[t + st];
        __syncthreads();
    }
    if (t == 0) bsum[b] = red[0];
}

// single block: exclusive scan of bsum[0..NB) in place (NB <= 256); offs[E] = T
__global__ void scan_partials(int* __restrict__ bsum, int NB,
                              int* __restrict__ offs, int E, int T)
{
    __shared__ int sh[256];
    int t = threadIdx.x;
    int v = (t < NB) ? bsum[t] : 0;
    sh[t] = v;
    __syncthreads();
    for (int d = 1; d < 256; d <<= 1) {
        int x = (t >= d) ? sh[t - d] : 0;
        __syncthreads();
        sh[t] += x;
        __syncthreads();
    }
    if (t < NB) bsum[t] = sh[t] - v;   // exclusive
    if (t == 0) offs[E] = T;
}

__global__ __launch_bounds__(256)
void scan_chunks(const int* __restrict__ cnt, const int* __restrict__ bsum,
                 int* __restrict__ offs, int E)
{
    __shared__ int sh[256];
    int b = blockIdx.x, t = threadIdx.x;
    int base = b * SCHUNK + t * 8;
    int loc[8];
    int s = 0;
    for (int i = 0; i < 8; ++i) {
        int idx = base + i;
        loc[i] = (idx < E) ? cnt[idx] : 0;
    }
    for (int i = 0; i < 8; ++i) { int v = loc[i]; loc[i] = s; s += v; }
    sh[t] = s;
    __syncthreads();
    for (int d = 1; d < 256; d <<= 1) {
        int x = (t >= d) ? sh[t - d] : 0;
        __syncthreads();
        sh[t] += x;
        __syncthreads();
    }
    int ex = sh[t] - s;                // exclusive over threads
    int off = bsum[b] + ex;
    for (int i = 0; i < 8; ++i) {
        int idx = base + i;
        if (idx < E) offs[idx] = off + loc[i];
    }
}

__global__ __launch_bounds__(256)
void fill_k(const int* __restrict__ kidx, const int* __restrict__ offs,
            int* __restrict__ cur, int* __restrict__ blist, int T)
{
    for (int t = blockIdx.x * 256 + threadIdx.x; t < T; t += gridDim.x * 256) {
        int k = kidx[t];
        int pos = offs[k] + atomicAdd(&cur[k], 1);
        blist[pos] = t;
    }
}

// update = silu(bn(core)) * sigmoid(bn(gate)); segment-sum via CSR gather.
// One wave per edge; single coalesced float2 store per edge -- zero global atomics.
__global__ __launch_bounds__(256)
void seg_update(const u16* __restrict__ CG, const float* __restrict__ ab,
                const int* __restrict__ offs, const int* __restrict__ blist,
                float* __restrict__ acc, int E)
{
    const int tid = threadIdx.x;
    const int q = tid & 63;
    const int wv = tid >> 6;
    const int f = q * 2;
    const float ac0 = ab[f], ac1 = ab[f + 1];
    const float ag0 = ab[128 + f], ag1 = ab[128 + f + 1];
    const float bc0 = ab[256 + f], bc1 = ab[256 + f + 1];
    const float bg0 = ab[384 + f], bg1 = ab[384 + f + 1];
    for (int e = blockIdx.x * 4 + wv; e < E; e += gridDim.x * 4) {
        int s = offs[e], en = offs[e + 1];
        float u0 = 0.f, u1 = 0.f;
        for (int idx = s; idx < en; ++idx) {
            int t = blist[idx];
            u32 c2 = *(const u32*)(CG + (size_t)t * 256 + f);
            u32 g2 = *(const u32*)(CG + (size_t)t * 256 + 128 + f);
            float c0 = bf2f((u16)(c2 & 0xffffu)) * ac0 + bc0;
            float c1 = bf2f((u16)(c2 >> 16)) * ac1 + bc1;
            float g0 = bf2f((u16)(g2 & 0xffffu)) * ag0 + bg0;
            float g1 = bf2f((u16)(g2 >> 16)) * ag1 + bg1;
            float s0 = 1.f / (1.f + __expf(-c0));
            float s1 = 1.f / (1.f + __expf(-c1));
            float t0 = 1.f / (1.f + __expf(-g0));
            float t1 = 1.f / (1.f + __expf(-g1));
            u0 += c0 * s0 * t0;
            u1 += c1 * s1 * t1;
        }
        *(float2*)(acc + (size_t)e * 128 + f) = make_float2(u0, u1);
    }
}

// Out[M][128] = fp32acc[M][128] @ W[128][128]^T + Edge[M][128]
__global__ __launch_bounds__(256)
void gemm_out(const float* __restrict__ Aacc, const void* __restrict__ Wv_,
              const void* __restrict__ Edgev, void* __restrict__ Outv,
              const int* __restrict__ flag, int M)
{
    __shared__ u16 As[BM][LSTR];
    __shared__ u16 Ws[BN][LSTR];
    const bool isf32 = flag[0] != 0;
    const int tid = threadIdx.x;
    const int m0 = blockIdx.x * BM;
    const int wave = tid >> 6, lane = tid & 63;
    const int l16 = lane & 15, quad = lane >> 4;
    const int wrow = (wave >> 1) * 64, wcol = (wave & 1) * 64;

    f32x4 acc[4][4];
    for (int mi = 0; mi < 4; ++mi)
        for (int ni = 0; ni < 4; ++ni)
            for (int r = 0; r < 4; ++r) acc[mi][ni][r] = 0.f;

    for (int kk = 0; kk < 128; kk += BK) {
        for (int it = 0; it < 4; ++it) {
            int c = tid + it * 256;
            int row = c >> 3, col8 = (c & 7) * 8;
            int gr = m0 + row;
            uint4 v = make_uint4(0, 0, 0, 0);
            if (gr < M) {
                const float* src = Aacc + (size_t)gr * 128 + kk + col8;
                v = make_uint4(pk2(src[0], src[1]), pk2(src[2], src[3]),
                               pk2(src[4], src[5]), pk2(src[6], src[7]));
            }
            *(uint4*)(&As[row][col8]) = v;
        }
        for (int it = 0; it < 4; ++it) {
            int c = tid + it * 256;
            int row = c >> 3, col8 = (c & 7) * 8;
            uint4 v;
            if (!isf32) {
                v = *(const uint4*)((const u16*)Wv_ + (size_t)row * 128 + (kk + col8));
            } else {
                const float* Wf = (const float*)Wv_ + (size_t)row * 128 + (kk + col8);
                float4 x = *(const float4*)Wf;
                float4 y = *(const float4*)(Wf + 4);
                v = make_uint4(pk2(x.x, x.y), pk2(x.z, x.w), pk2(y.x, y.y), pk2(y.z, y.w));
            }
            *(uint4*)(&Ws[row][col8]) = v;
        }
        __syncthreads();
        for (int ko = 0; ko < BK; ko += 32) {
            bf8 af[4], bw[4];
            for (int mi = 0; mi < 4; ++mi)
                af[mi] = *(const bf8*)(&As[wrow + mi * 16 + l16][ko + quad * 8]);
            for (int ni = 0; ni < 4; ++ni)
                bw[ni] = *(const bf8*)(&Ws[wcol + ni * 16 + l16][ko + quad * 8]);
            for (int mi = 0; mi < 4; ++mi)
                for (int ni = 0; ni < 4; ++ni)
                    acc[mi][ni] = __builtin_amdgcn_mfma_f32_16x16x32_bf16(
                        af[mi], bw[ni], acc[mi][ni], 0, 0, 0);
        }
        __syncthreads();
    }
    for (int mi = 0; mi < 4; ++mi) {
        int rbase = m0 + wrow + mi * 16 + quad * 4;
        for (int r = 0; r < 4; ++r) {
            int row = rbase + r;
            if (row >= M) continue;
            for (int ni = 0; ni < 4; ++ni) {
                int col = wcol + ni * 16 + l16;
                size_t idx = (size_t)row * 128 + col;
                float e = isf32 ? ((const float*)Edgev)[idx] : bf2f(((const u16*)Edgev)[idx]);
                float v = acc[mi][ni][r] + e;
                if (isf32) ((float*)Outv)[idx] = v;
                else       ((u16*)Outv)[idx] = f2bf(v);
            }
        }
    }
}

// Wv rows: [0:128)=w_core_src [128:256)=w_gate_src [256:384)=w_core_dst [384:512)=w_gate_dst
// We rows: [0:128)=w_core_bond [128:256)=w_gate_bond
// Wa rows: [0:128)=w_core_angle [128:256)=w_gate_angle (K=64)
__device__ __forceinline__ u16 ld_bf(const void* p, size_t idx, bool isf32)
{
    return isf32 ? f2bf(((const float*)p)[idx]) : ((const u16*)p)[idx];
}

__global__ void pack_weights(const void* __restrict__ wcs, const void* __restrict__ wcd,
                             const void* __restrict__ wcb, const void* __restrict__ wca,
                             const void* __restrict__ wgs, const void* __restrict__ wgd,
                             const void* __restrict__ wgb, const void* __restrict__ wga,
                             u16* __restrict__ Wv, u16* __restrict__ We, u16* __restrict__ Wa,
                             const int* __restrict__ flag)
{
    const bool isf32 = flag[0] != 0;
    int tid = blockIdx.x * 256 + threadIdx.x;  // 65536 threads
    {
        int row = tid >> 7, col = tid & 127;
        const void* src = (row < 128) ? wcs : (row < 256) ? wgs : (row < 384) ? wcd : wgd;
        Wv[tid] = ld_bf(src, (size_t)(row & 127) * 128 + col, isf32);
    }
    if (tid < 256 * 128) {
        int row = tid >> 7, col = tid & 127;
        const void* src = (row < 128) ? wcb : wgb;
        We[tid] = ld_bf(src, (size_t)(row & 127) * 128 + col, isf32);
    }
    if (tid < 256 * 64) {
        int row = tid >> 6, col = tid & 63;
        const void* src = (row < 128) ? wca : wga;
        Wa[tid] = ld_bf(src, (size_t)(row & 127) * 64 + col, isf32);
    }
}

extern "C" void kernel_launch(void* const* d_in, const int* in_sizes, int n_in,
                              void* d_out, int out_size, void* d_ws, size_t ws_size,
                              hipStream_t stream)
{
    const void* vertex = d_in[0];
    const void* edge   = d_in[1];
    const void* angle  = d_in[2];
    // d_in[3] = edge_index (unused by the reference computation)
    const int* kidx = (const int*)d_in[4];
    const int* jidx = (const int*)d_in[5];
    const int* iidx = (const int*)d_in[6];

    const int N = in_sizes[0] / 128;
    const int E = in_sizes[1] / 128;
    const int T = in_sizes[2] / 64;

    char* p = (char*)d_ws;
    auto alloc = [&](size_t bytes) {
        char* r = p;
        p += (bytes + 255) & ~(size_t)255;
        return r;
    };
    u16* Wv = (u16*)alloc((size_t)512 * 128 * 2);
    u16* We = (u16*)alloc((size_t)256 * 128 * 2);
    u16* Wa = (u16*)alloc((size_t)256 * 64 * 2);
    float* stats = (float*)alloc(512 * 4);
    float* ab = (float*)alloc(512 * 4);
    int* flag = (int*)alloc(256);
    u16* Vout = (u16*)alloc((size_t)N * 512 * 2);   // dead after gather_stats
    u16* Eout = (u16*)alloc((size_t)E * 256 * 2);   // dead after gather_stats
    u16* CG   = (u16*)alloc((size_t)T * 256 * 2);   // angle GEMM out, then core|gate in place
    float* acc = (float*)Vout;                      // aliases Vout+Eout (307MB >= 204.8MB)

    // CSR arrays live in the Vout/Eout region BEYOND acc (102.4MB free there);
    // only touched after gather_stats (when Vout/Eout are dead).
    char* tail = (char*)acc + (size_t)E * 512;      // E*128*4, multiple of 256
    int* cnt   = (int*)tail;                        // E ints (histogram, then cursor)
    int* offs  = cnt + ((E + 63) & ~63);            // E+1 ints
    int* blist = offs + ((E + 1 + 63) & ~63);       // T ints
    int* bsum  = blist + ((T + 63) & ~63);          // <=256 ints
    const int NB = (E + SCHUNK - 1) / SCHUNK;       // 196 for E=400000 (<=256)

    hipMemsetAsync(stats, 0, 512 * 4, stream);
    detect_dtype<<<1, 256, 0, stream>>>((const u16*)vertex, flag);
    pack_weights<<<256, 256, 0, stream>>>(d_in[7], d_in[8], d_in[9], d_in[10],
                                          d_in[11], d_in[12], d_in[13], d_in[14],
                                          Wv, We, Wa, flag);
    gemm_bt<<<dim3(4, (N + 127) / 128), 256, 0, stream>>>(vertex, Wv, Vout, flag, N, 128, 512);
    gemm_bt<<<dim3(2, (E + 127) / 128), 256, 0, stream>>>(edge, We, Eout, flag, E, 128, 256);
    gemm_bt<<<dim3(2, (T + 127) / 128), 256, 0, stream>>>(angle, Wa, CG, flag, T, 64, 256);
    gather_stats<<<2048, 256, 0, stream>>>(CG, Vout, Eout, jidx, kidx, iidx, stats, T);

    // Vout/Eout dead: build CSR of kidx in the freed region.
    hipMemsetAsync(cnt, 0, (size_t)E * 4, stream);
    hist_k<<<2048, 256, 0, stream>>>(kidx, cnt, T);
    scan_blocks<<<NB, 256, 0, stream>>>(cnt, bsum, E);
    scan_partials<<<1, 256, 0, stream>>>(bsum, NB, offs, E, T);
    scan_chunks<<<NB, 256, 0, stream>>>(cnt, bsum, offs, E);
    hipMemsetAsync(cnt, 0, (size_t)E * 4, stream);  // reuse as fill cursor
    fill_k<<<2048, 256, 0, stream>>>(kidx, offs, cnt, blist, T);

    bn_finalize<<<1, 256, 0, stream>>>(stats, d_in[15], d_in[16], d_in[17], d_in[18],
                                       ab, flag, 1.0f / (float)T);
    seg_update<<<2048, 256, 0, stream>>>(CG, ab, offs, blist, acc, E);
    gemm_out<<<dim3((E + 127) / 128, 1), 256, 0, stream>>>(acc, d_in[19], edge, d_out, flag, E);
}